// Round 1
// baseline (108.964 us; speedup 1.0000x reference)
//
#include <hip/hip_runtime.h>
#include <math.h>

#define BLK 256
#define IT 4
#define JSPLIT 128
#define NITILE 8          // N / (BLK*IT)
#define BBLK 128
#define BGRID 64          // BGRID*BBLK == N
#define LAM 0.1f

// ws layout (floats):
//   rowsP[5][JSPLIT][N]   = 5*128*8192 floats (21 MB) raw per-jsp row partials
//   tceP [NITILE*JSPLIT][4]  per-block T_ce partials (plain stores)
//   momP [NITILE][12]        focal/W/M1/M2 partials from jsp==0 blocks
//   scalB[20]                0..13 acc sums, 14..17 T_ce sums, 18 ticket, 19 pad

__device__ __forceinline__ float wave_reduce(float v) {
    v += __shfl_down(v, 32, 64);
    v += __shfl_down(v, 16, 64);
    v += __shfl_down(v, 8, 64);
    v += __shfl_down(v, 4, 64);
    v += __shfl_down(v, 2, 64);
    v += __shfl_down(v, 1, 64);
    return v;
}

// ---------------- kernel A: fused softmax + moments + O(N^2) pairs ----------
// grid (NITILE, JSPLIT) = (8, 128) = 1024 blocks, 4 blocks/CU, 16 waves/CU
__global__ __launch_bounds__(BLK) void kA(
        const float* __restrict__ outs, const int* __restrict__ labels,
        const float* __restrict__ event, const float* __restrict__ wts,
        float* __restrict__ rowsP, float* __restrict__ tceP,
        float* __restrict__ momP, float* __restrict__ scalB, int N) {
    __shared__ float4 jp[64];
    __shared__ float2 jew[64];
    __shared__ float red4[4][4];
    __shared__ float red12[4][12];

    int tid = threadIdx.x;
    int itile = blockIdx.x;        // 0..7
    int jsp = blockIdx.y;          // 0..127
    int ibase = itile * (BLK * IT) + tid;

    // zero cross-kernel accumulators + ticket (visible to kB via stream order)
    if (itile == 0 && jsp == 0 && tid < 20) scalB[tid] = 0.f;

    // ---- j-side: softmax for this block's 64 j's, straight into LDS ----
    if (tid < 64) {
        int j = jsp * 64 + tid;
        float4 o = ((const float4*)outs)[j];
        float m = fmaxf(fmaxf(o.x, o.y), fmaxf(o.z, o.w));
        float e0 = expf(o.x - m), e1 = expf(o.y - m),
              e2 = expf(o.z - m), e3 = expf(o.w - m);
        float inv = 1.0f / (e0 + e1 + e2 + e3);
        jp[tid] = make_float4(e0 * inv, e1 * inv, e2 * inv, e3 * inv);
        jew[tid] = make_float2(event[j], wts[j]);
    }

    // ---- i-side: softmax for IT rows per thread (registers) ----
    float4 pi[IT];
    float ei[IT], wi[IT];
#pragma unroll
    for (int k = 0; k < IT; ++k) {
        int i = ibase + k * BLK;
        float4 o = ((const float4*)outs)[i];
        float m = fmaxf(fmaxf(o.x, o.y), fmaxf(o.z, o.w));
        float e0 = expf(o.x - m), e1 = expf(o.y - m),
              e2 = expf(o.z - m), e3 = expf(o.w - m);
        float inv = 1.0f / (e0 + e1 + e2 + e3);
        pi[k] = make_float4(e0 * inv, e1 * inv, e2 * inv, e3 * inv);
        ei[k] = event[i];
        wi[k] = wts[i];
    }

    // ---- focal + moment partials: only the 8 jsp==0 blocks (old k1) ----
    if (jsp == 0) {
        float acc12[12];
#pragma unroll
        for (int k = 0; k < 12; ++k) acc12[k] = 0.f;
#pragma unroll
        for (int k = 0; k < IT; ++k) {
            int i = ibase + k * BLK;
            float4 o = ((const float4*)outs)[i];
            float m = fmaxf(fmaxf(o.x, o.y), fmaxf(o.z, o.w));
            float e0 = expf(o.x - m), e1 = expf(o.y - m),
                  e2 = expf(o.z - m), e3 = expf(o.w - m);
            float s = e0 + e1 + e2 + e3;
            int l = labels[i];
            float ol = (l == 0) ? o.x : (l == 1) ? o.y : (l == 2) ? o.z : o.w;
            float logpt = ol - m - logf(s);
            float pt = expf(logpt);
            float om = 1.0f - pt;
            float w = wi[k], ev = ei[k];
            float4 p = pi[k];
            acc12[0] += -om * om * logpt * w;
            acc12[1] += w;
            acc12[2] += w * p.x;  acc12[3] += w * p.y;
            acc12[4] += w * p.z;  acc12[5] += w * p.w;
            acc12[6] += w * ev;
            acc12[7] += w * p.x * p.x;  acc12[8] += w * p.y * p.y;
            acc12[9] += w * p.z * p.z;  acc12[10] += w * p.w * p.w;
            acc12[11] += w * ev * ev;
        }
        int lane = tid & 63, wave = tid >> 6;
#pragma unroll
        for (int k = 0; k < 12; ++k) {
            float r = wave_reduce(acc12[k]);
            if (lane == 0) red12[wave][k] = r;
        }
        __syncthreads();
        if (tid < 12)
            momP[itile * 12 + tid] =
                red12[0][tid] + red12[1][tid] + red12[2][tid] + red12[3][tid];
    }
    __syncthreads();   // jp/jew ready for everyone

    // ---- pair loop: identical proven 15-op inner body ----
    float s[IT][5], t[IT][4];
#pragma unroll
    for (int k = 0; k < IT; ++k) {
#pragma unroll
        for (int v = 0; v < 5; ++v) s[k][v] = 0.f;
#pragma unroll
        for (int v = 0; v < 4; ++v) t[k][v] = 0.f;
    }

#pragma unroll 8
    for (int jj = 0; jj < 64; ++jj) {
        float4 p = jp[jj];
        float2 ew = jew[jj];
        float wj = ew.y;
#pragma unroll
        for (int k = 0; k < IT; ++k) {
            float d0 = pi[k].x - p.x;
            float d1 = pi[k].y - p.y;
            float d2 = pi[k].z - p.z;
            float d3 = pi[k].w - p.w;
            float de = ei[k] - ew.x;
            s[k][0] = fmaf(wj, fabsf(d0), s[k][0]);
            s[k][1] = fmaf(wj, fabsf(d1), s[k][1]);
            s[k][2] = fmaf(wj, fabsf(d2), s[k][2]);
            s[k][3] = fmaf(wj, fabsf(d3), s[k][3]);
            float wde = wj * fabsf(de);
            s[k][4] += wde;
            t[k][0] = fmaf(wde, fabsf(d0), t[k][0]);
            t[k][1] = fmaf(wde, fabsf(d1), t[k][1]);
            t[k][2] = fmaf(wde, fabsf(d2), t[k][2]);
            t[k][3] = fmaf(wde, fabsf(d3), t[k][3]);
        }
    }

    // ---- raw row partials: plain coalesced stores, NO atomics, no zero-init ----
#pragma unroll
    for (int k = 0; k < IT; ++k) {
        int i = ibase + k * BLK;
#pragma unroll
        for (int v = 0; v < 5; ++v)
            rowsP[(v * JSPLIT + jsp) * N + i] = s[k][v];
    }

    // ---- T_ce partial: block-reduce, plain store (no atomic, no zero-init) ----
    float tc0 = t[0][0] * wi[0] + t[1][0] * wi[1] + t[2][0] * wi[2] + t[3][0] * wi[3];
    float tc1 = t[0][1] * wi[0] + t[1][1] * wi[1] + t[2][1] * wi[2] + t[3][1] * wi[3];
    float tc2 = t[0][2] * wi[0] + t[1][2] * wi[1] + t[2][2] * wi[2] + t[3][2] * wi[3];
    float tc3 = t[0][3] * wi[0] + t[1][3] * wi[1] + t[2][3] * wi[2] + t[3][3] * wi[3];
    int lane = tid & 63, wave = tid >> 6;
    tc0 = wave_reduce(tc0); tc1 = wave_reduce(tc1);
    tc2 = wave_reduce(tc2); tc3 = wave_reduce(tc3);
    if (lane == 0) {
        red4[wave][0] = tc0; red4[wave][1] = tc1;
        red4[wave][2] = tc2; red4[wave][3] = tc3;
    }
    __syncthreads();
    if (tid < 4)
        tceP[(jsp * NITILE + itile) * 4 + tid] =
            red4[0][tid] + red4[1][tid] + red4[2][tid] + red4[3][tid];
}

// ---------------- kernel B: row reduction + weighted sums + final ------------
// 64 blocks x 128 threads, one thread per i. Last block (ticket) does scalars.
__global__ __launch_bounds__(BBLK) void kB(
        const float* __restrict__ rowsP, const float* __restrict__ tceP,
        const float* __restrict__ momP, const float* __restrict__ wts,
        float* __restrict__ scalB, float* __restrict__ out, int N) {
    __shared__ float red[2][14];
    __shared__ float fin[12];
    __shared__ float sc[18];
    __shared__ unsigned int last;

    int tid = threadIdx.x;
    int i = blockIdx.x * BBLK + tid;

    float s0 = 0.f, s1 = 0.f, s2 = 0.f, s3 = 0.f, sE = 0.f;
#pragma unroll 8
    for (int jsp = 0; jsp < JSPLIT; ++jsp) {
        s0 += rowsP[(0 * JSPLIT + jsp) * N + i];
        s1 += rowsP[(1 * JSPLIT + jsp) * N + i];
        s2 += rowsP[(2 * JSPLIT + jsp) * N + i];
        s3 += rowsP[(3 * JSPLIT + jsp) * N + i];
        sE += rowsP[(4 * JSPLIT + jsp) * N + i];
    }

    float w = wts[i];
    float a[14];
    a[0] = w * s0; a[1] = w * s1; a[2] = w * s2; a[3] = w * s3; a[4] = w * sE;
    float wE = w * sE;
    a[5] = wE * s0; a[6] = wE * s1; a[7] = wE * s2; a[8] = wE * s3; a[9] = wE * sE;
    a[10] = w * s0 * s0; a[11] = w * s1 * s1;
    a[12] = w * s2 * s2; a[13] = w * s3 * s3;

    int lane = tid & 63, wave = tid >> 6;
#pragma unroll
    for (int k = 0; k < 14; ++k) {
        float r = wave_reduce(a[k]);
        if (lane == 0) red[wave][k] = r;
    }
    __syncthreads();
    if (tid < 14) atomicAdd(&scalB[tid], red[0][tid] + red[1][tid]);

    // T_ce partial reduction: 1024 rows / 64 blocks = 16 rows per block
    if (tid < 64) {
        float v = tceP[(blockIdx.x * 16 + (tid >> 2)) * 4 + (tid & 3)];
        v += __shfl_down(v, 32, 64);
        v += __shfl_down(v, 16, 64);
        v += __shfl_down(v, 8, 64);
        v += __shfl_down(v, 4, 64);
        if (tid < 4) atomicAdd(&scalB[14 + tid], v);
    }

    __syncthreads();               // all this block's atomics complete (vmcnt drained)
    if (tid == 0) {
        __threadfence();           // publish before ticket
        last = atomicAdd((unsigned int*)&scalB[18], 1u);
    }
    __syncthreads();
    if (last != BGRID - 1) return;

    // ---- last block: gather scalars + final math (old k3 tail) ----
    __threadfence();
    if (tid < 12) {
        float aa = 0.f;
#pragma unroll
        for (int tI = 0; tI < NITILE; ++tI) aa += momP[tI * 12 + tid];
        fin[tid] = aa;
    }
    if (tid < 18) sc[tid] = atomicAdd(&scalB[tid], 0.0f);  // coherent L2 read
    __syncthreads();

    if (tid == 0) {
        float SW[5]     = {sc[0], sc[1], sc[2], sc[3], sc[4]};
        float SWW_ce[4] = {sc[5], sc[6], sc[7], sc[8]};
        float SWW_ee    = sc[9];
        float SWW_cc[4] = {sc[10], sc[11], sc[12], sc[13]};

        float focal_sum = fin[0];
        float W = fin[1];
        float M1[5] = {fin[2], fin[3], fin[4], fin[5], fin[6]};
        float M2[5] = {fin[7], fin[8], fin[9], fin[10], fin[11]};

        float invW2 = 1.0f / (W * W);
        float invW3 = invW2 / W;

        float g[5];
#pragma unroll
        for (int v = 0; v < 5; ++v) g[v] = SW[v] * invW2;
        float gE = g[4];

        float Tee = 2.0f * (W * M2[4] - M1[4] * M1[4]);
        float num_ee = Tee * invW2 - 2.0f * SWW_ee * invW3 + gE * gE;

        float disco = 0.f;
#pragma unroll
        for (int c = 0; c < 4; ++c) {
            float Tcc = 2.0f * (W * M2[c] - M1[c] * M1[c]);
            float num_cc = Tcc * invW2 - 2.0f * SWW_cc[c] * invW3 + g[c] * g[c];
            float num_ce = sc[14 + c] * invW2 - 2.0f * SWW_ce[c] * invW3 + g[c] * gE;
            disco += num_ce * rsqrtf(num_cc * num_ee);
        }
        disco *= 0.25f;

        float f = focal_sum / (float)N;
        out[0] = f;
        out[1] = disco;
        out[2] = f + LAM * disco;
    }
}

extern "C" void kernel_launch(void* const* d_in, const int* in_sizes, int n_in,
                              void* d_out, int out_size, void* d_ws, size_t ws_size,
                              hipStream_t stream) {
    const float* outs = (const float*)d_in[0];
    const int* labels = (const int*)d_in[1];
    const float* event = (const float*)d_in[2];
    const float* wts = (const float*)d_in[3];
    float* out = (float*)d_out;
    int N = in_sizes[1];  // 8192

    float* ws = (float*)d_ws;
    float* rowsP = ws;                                    // 5*JSPLIT*N
    float* tceP = rowsP + (size_t)5 * JSPLIT * N;         // 1024*4
    float* momP = tceP + (size_t)NITILE * JSPLIT * 4;     // 8*12
    float* scalB = momP + NITILE * 12;                    // 20

    dim3 gA(N / (BLK * IT), JSPLIT);   // (8, 128) = 1024 blocks
    kA<<<gA, BLK, 0, stream>>>(outs, labels, event, wts, rowsP, tceP, momP, scalB, N);
    kB<<<BGRID, BBLK, 0, stream>>>(rowsP, tceP, momP, wts, scalB, out, N);
}